// Round 9
// baseline (114.616 us; speedup 1.0000x reference)
//
#include <hip/hip_runtime.h>
#include <math.h>

#define BB 1024
#define TT 1024
#define HH 256
#define CC 10
#define RB 4    // rows per block: ILP-4 per lane, 1 wave/SIMD, grid = 256

// State fold: track r where h = 1 - 2r.
//   z = wd*h + win*x + bh,  m = S*z  (S = 2*log2e)
//   m = A*r + q,  A = -2*wd*S,  q = fma(x, win*S, (bh + wd)*S)
//   t = exp2(m); r' = rcp(t + 1)
//
// Round-9: 1 wave/SIMD x ILP-4 PACKED — the last untried structural point.
// Round 4 (ILP-4 scalar) was confounded: scalar issue ~107cy/step. Packed:
// two INDEPENDENT pk-streams (chains 01, 23), issue ~76cy/step; each
// stream's trans work is filler the scheduler can place inside the other
// stream's 3 latency gaps (~16cy each) — in-stream hiding that ILP-2
// cannot do (its chains are welded into one pk dependency chain).
// x staged interleaved {x0,x1,x2,x3} per step: one ds_read_b128 feeds both
// pk pairs; distance-4..8 rolling prefetch into 8 named f4 buffers (zero
// rotation movs) covers the 1-wave LDS exposure that hurt round 4.

typedef float f2 __attribute__((ext_vector_type(2)));
typedef float f4 __attribute__((ext_vector_type(4)));

__global__ __launch_bounds__(HH, 1) void vanilla_rnn_kernel(
    const float* __restrict__ x,
    const float* __restrict__ W_hx,
    const float* __restrict__ W_hh,
    const float* __restrict__ b_h,
    const float* __restrict__ W_hp,
    const float* __restrict__ b_o,
    float* __restrict__ out)
{
    __shared__ f4 xsp[TT + 4];        // xsp[t] = {x0,x1,x2,x3}(t); +4 zero pad
    __shared__ float part[RB][CC * 4];

    const int tid = threadIdx.x;   // h index
    const int b0  = blockIdx.x * RB;

    // Stage 4 rows transposed/interleaved: thread tid covers steps 4tid..4tid+3.
    {
        f4 a4 = ((const f4*)(x + (size_t)(b0 + 0) * TT))[tid];
        f4 c4 = ((const f4*)(x + (size_t)(b0 + 1) * TT))[tid];
        f4 d4 = ((const f4*)(x + (size_t)(b0 + 2) * TT))[tid];
        f4 e4 = ((const f4*)(x + (size_t)(b0 + 3) * TT))[tid];
        xsp[4 * tid + 0] = (f4){a4.x, c4.x, d4.x, e4.x};
        xsp[4 * tid + 1] = (f4){a4.y, c4.y, d4.y, e4.y};
        xsp[4 * tid + 2] = (f4){a4.z, c4.z, d4.z, e4.z};
        xsp[4 * tid + 3] = (f4){a4.w, c4.w, d4.w, e4.w};
        if (tid < 4) xsp[TT + tid] = (f4){0.f, 0.f, 0.f, 0.f};
    }

    // Per-h constants (pre-scaled by S = 2*log2(e)) — shared by all 4 chains.
    const float S    = 2.88539008177792681472f;
    const float winS = W_hx[tid] * S;
    const float wd   = W_hh[tid * HH + tid];
    const float bhS2 = (b_h[tid] + wd) * S;
    const f2 A2   = (f2){-2.0f * wd * S, -2.0f * wd * S};
    const f2 win2 = (f2){winS, winS};
    const f2 bh2  = (f2){bhS2, bhS2};
    const f2 one2 = (f2){1.0f, 1.0f};
    float whp[CC];
#pragma unroll
    for (int c = 0; c < CC; ++c) whp[c] = W_hp[c * HH + tid];

    __syncthreads();

    f2 r01 = (f2){0.5f, 0.5f};            // h0 = 0  =>  r = 0.5
    f2 r23 = (f2){0.5f, 0.5f};

    // One step of all 4 chains: two independent pk-streams.
#define STEP(XV) {                                        \
        f2 q01 = __builtin_elementwise_fma((XV).xy, win2, bh2); \
        f2 q23 = __builtin_elementwise_fma((XV).zw, win2, bh2); \
        f2 m01 = __builtin_elementwise_fma(A2, r01, q01); \
        f2 m23 = __builtin_elementwise_fma(A2, r23, q23); \
        f2 t01, t23;                                      \
        t01.x = __builtin_amdgcn_exp2f(m01.x);            \
        t01.y = __builtin_amdgcn_exp2f(m01.y);            \
        t23.x = __builtin_amdgcn_exp2f(m23.x);            \
        t23.y = __builtin_amdgcn_exp2f(m23.y);            \
        f2 u01 = t01 + one2;                              \
        f2 u23 = t23 + one2;                              \
        r01.x = __builtin_amdgcn_rcpf(u01.x);             \
        r01.y = __builtin_amdgcn_rcpf(u01.y);             \
        r23.x = __builtin_amdgcn_rcpf(u23.x);             \
        r23.y = __builtin_amdgcn_rcpf(u23.y); }

    // 8 steps/iter, 8 named buffers, rolling loads (no rotation movs).
    // Prefetch distance 4..8 steps; tail loads (k=248: idx 256..259) land
    // in the 4-entry zero pad.
    f4 v0 = xsp[0], v1 = xsp[1], v2 = xsp[2], v3 = xsp[3];
    for (int k = 0; k < TT; k += 8) {
        f4 v4 = xsp[k + 4], v5 = xsp[k + 5], v6 = xsp[k + 6], v7 = xsp[k + 7];
        STEP(v0) STEP(v1) STEP(v2) STEP(v3)
        v0 = xsp[k + 8];  v1 = xsp[k + 9];
        v2 = xsp[k + 10]; v3 = xsp[k + 11];   // last iter: zero pad
        STEP(v4) STEP(v5) STEP(v6) STEP(v7)
    }
#undef STEP

    const float h0 = fmaf(-2.0f, r01.x, 1.0f);
    const float h1 = fmaf(-2.0f, r01.y, 1.0f);
    const float h2 = fmaf(-2.0f, r23.x, 1.0f);
    const float h3 = fmaf(-2.0f, r23.y, 1.0f);

    // Projection: out[b,c] = sum_h h * W_hp[c,h] + b_o[c]  (all 4 rows)
    const int lane = tid & 63;
    const int wave = tid >> 6;
#pragma unroll
    for (int c = 0; c < CC; ++c) {
        float p0 = h0 * whp[c];
        float p1 = h1 * whp[c];
        float p2 = h2 * whp[c];
        float p3 = h3 * whp[c];
#pragma unroll
        for (int off = 32; off >= 1; off >>= 1) {
            p0 += __shfl_down(p0, off);
            p1 += __shfl_down(p1, off);
            p2 += __shfl_down(p2, off);
            p3 += __shfl_down(p3, off);
        }
        if (lane == 0) {
            part[0][c * 4 + wave] = p0;
            part[1][c * 4 + wave] = p1;
            part[2][c * 4 + wave] = p2;
            part[3][c * 4 + wave] = p3;
        }
    }
    __syncthreads();

    if (tid < RB * CC) {
        const int bb = tid / CC;      // which batch row
        const int c  = tid - bb * CC;
        float acc = b_o[c];
#pragma unroll
        for (int w = 0; w < 4; ++w) acc += part[bb][c * 4 + w];
        out[(size_t)(b0 + bb) * CC + c] = acc;
    }
}

extern "C" void kernel_launch(void* const* d_in, const int* in_sizes, int n_in,
                              void* d_out, int out_size, void* d_ws, size_t ws_size,
                              hipStream_t stream) {
    const float* x    = (const float*)d_in[0];
    const float* W_hx = (const float*)d_in[1];
    const float* W_hh = (const float*)d_in[2];
    const float* b_h  = (const float*)d_in[3];
    const float* W_hp = (const float*)d_in[4];
    const float* b_o  = (const float*)d_in[5];
    float* out = (float*)d_out;

    vanilla_rnn_kernel<<<BB / RB, HH, 0, stream>>>(x, W_hx, W_hh, b_h, W_hp, b_o, out);
}

// Round 10
// 110.915 us; speedup vs baseline: 1.0334x; 1.0334x over previous
//
#include <hip/hip_runtime.h>
#include <math.h>

#define BB 1024
#define TT 1024
#define HH 256
#define CC 10

// State fold: track r where h = 1 - 2r.
//   z = wd*h + win*x + bh,  m = S*z  (S = 2*log2e)
//   m = A*r + q,  A = -2*wd*S,  q = fma(x, win*S, (bh + wd)*S)
//   t = exp2(m); r' = rcp(t + 1)
// Loop-carried chain: fma -> exp2 -> add -> rcp (4 ops), per chain.
//
// Round-10 = REVERT to round-6 (session best: 55.4us dispatch).
// Full structural map (cy/step/SIMD, 4 chains/SIMD fixed by problem shape):
//   4wx1 scalar 145 | 2wx2 scalar 146 | 2wx2 pk 130 (BEST) |
//   de-pair rr 159 | pk+stagger 133 | 1wx4 pk 140 | NR-rcp 194
// busy(85) = issue model (trans 1/4-rate); stall(~45) invariant under all
// scheduling levers -> trans result-latency floor. This config minimizes
// busy; weld/unweld is a measured wash on stall. Floor ~= 130 cy/step.

typedef float f2 __attribute__((ext_vector_type(2)));
typedef float f4 __attribute__((ext_vector_type(4)));

__global__ __launch_bounds__(HH) void vanilla_rnn_kernel(
    const float* __restrict__ x,
    const float* __restrict__ W_hx,
    const float* __restrict__ W_hh,
    const float* __restrict__ b_h,
    const float* __restrict__ W_hp,
    const float* __restrict__ b_o,
    float* __restrict__ out)
{
    __shared__ f4 xsp[TT / 2 + 2];        // interleaved pairs {A,B,A,B}; +2 f4 pad
    __shared__ float part[2][CC * 4];

    const int tid = threadIdx.x;   // h index
    const int b0  = blockIdx.x * 2;

    // Stage both rows interleaved: xsp[k] = {A(2k), B(2k), A(2k+1), B(2k+1)}.
    {
        f4 a4 = ((const f4*)(x + (size_t)b0 * TT))[tid];
        f4 b4 = ((const f4*)(x + (size_t)(b0 + 1) * TT))[tid];
        xsp[2 * tid]     = (f4){a4.x, b4.x, a4.y, b4.y};
        xsp[2 * tid + 1] = (f4){a4.z, b4.z, a4.w, b4.w};
        if (tid < 2) xsp[TT / 2 + tid] = (f4){0.f, 0.f, 0.f, 0.f};
    }

    // Per-h constants (pre-scaled by S = 2*log2(e)) — shared by both chains.
    const float S    = 2.88539008177792681472f;
    const float winS = W_hx[tid] * S;
    const float wd   = W_hh[tid * HH + tid];
    const float bhS2 = (b_h[tid] + wd) * S;
    const f2 A2   = (f2){-2.0f * wd * S, -2.0f * wd * S};
    const f2 win2 = (f2){winS, winS};
    const f2 bh2  = (f2){bhS2, bhS2};
    const f2 one2 = (f2){1.0f, 1.0f};
    float whp[CC];
#pragma unroll
    for (int c = 0; c < CC; ++c) whp[c] = W_hp[c * HH + tid];

    __syncthreads();

    f2 r = (f2){0.5f, 0.5f};              // h0 = 0  =>  r = 0.5

#define STEP(XPAIR) {                                   \
        f2 xv = (XPAIR);                                \
        f2 q  = __builtin_elementwise_fma(xv, win2, bh2); \
        f2 m  = __builtin_elementwise_fma(A2, r, q);    \
        f2 t;                                           \
        t.x = __builtin_amdgcn_exp2f(m.x);              \
        t.y = __builtin_amdgcn_exp2f(m.y);              \
        f2 u = t + one2;                                \
        r.x = __builtin_amdgcn_rcpf(u.x);               \
        r.y = __builtin_amdgcn_rcpf(u.y); }

    // Ping-pong named registers, k += 4 (8 time-steps per iter), loads land
    // directly in va/vb/vc/vd — no rotation movs. Prefetch distance = 4
    // steps (~150 cy issue) >= LDS latency; tail loads land in the pad.
    f4 va = xsp[0], vb = xsp[1];
    for (int k = 0; k < TT / 2; k += 4) {
        f4 vc = xsp[k + 2], vd = xsp[k + 3];
        STEP(va.xy) STEP(va.zw) STEP(vb.xy) STEP(vb.zw)
        va = xsp[k + 4]; vb = xsp[k + 5];   // last iter: reads the zero pad
        STEP(vc.xy) STEP(vc.zw) STEP(vd.xy) STEP(vd.zw)
    }
#undef STEP

    const float h0 = fmaf(-2.0f, r.x, 1.0f);
    const float h1 = fmaf(-2.0f, r.y, 1.0f);

    // Projection: out[b,c] = sum_h h * W_hp[c,h] + b_o[c]  (both rows)
    const int lane = tid & 63;
    const int wave = tid >> 6;
#pragma unroll
    for (int c = 0; c < CC; ++c) {
        float v0 = h0 * whp[c];
        float v1 = h1 * whp[c];
#pragma unroll
        for (int off = 32; off >= 1; off >>= 1) {
            v0 += __shfl_down(v0, off);
            v1 += __shfl_down(v1, off);
        }
        if (lane == 0) { part[0][c * 4 + wave] = v0; part[1][c * 4 + wave] = v1; }
    }
    __syncthreads();

    if (tid < 2 * CC) {
        const int bb = tid / CC;      // 0 or 1: which batch row
        const int c  = tid - bb * CC;
        float acc = b_o[c];
#pragma unroll
        for (int w = 0; w < 4; ++w) acc += part[bb][c * 4 + w];
        out[(size_t)(b0 + bb) * CC + c] = acc;
    }
}

extern "C" void kernel_launch(void* const* d_in, const int* in_sizes, int n_in,
                              void* d_out, int out_size, void* d_ws, size_t ws_size,
                              hipStream_t stream) {
    const float* x    = (const float*)d_in[0];
    const float* W_hx = (const float*)d_in[1];
    const float* W_hh = (const float*)d_in[2];
    const float* b_h  = (const float*)d_in[3];
    const float* W_hp = (const float*)d_in[4];
    const float* b_o  = (const float*)d_in[5];
    float* out = (float*)d_out;

    vanilla_rnn_kernel<<<BB / 2, HH, 0, stream>>>(x, W_hx, W_hh, b_h, W_hp, b_o, out);
}